// Round 12
// baseline (36536.676 us; speedup 1.0000x reference)
//
#include <hip/hip_runtime.h>
#include <stdint.h>

#define NBLK 256
#define NTHR 512

typedef _Float16 f16;
typedef _Float16 f16x8 __attribute__((ext_vector_type(8)));
typedef float f32x4 __attribute__((ext_vector_type(4)));
typedef unsigned long long u64;

// ---------------- helpers ----------------

__device__ __forceinline__ void split2(float w, f16& hi, f16& lo) {
  f16 h = (__builtin_fabsf(w) < 6.104e-05f) ? (f16)0.0f : (f16)w;
  hi = h;
  lo = (f16)((w - (float)h) * 2048.0f);
}

__device__ __forceinline__ void split3(float w, f16& h, f16& l, f16& m) {
  const float hf = (__builtin_fabsf(w) < 6.104e-05f) ? 0.0f : (float)(f16)w;
  h = (f16)hf;
  const float r1s = (w - hf) * 2048.0f;
  const float lf = (__builtin_fabsf(r1s) < 6.104e-05f) ? 0.0f : (float)(f16)r1s;
  l = (f16)lf;
  const float r2s = (r1s - lf) * 2048.0f;
  m = (__builtin_fabsf(r2s) < 6.104e-05f) ? (f16)0.0f : (f16)r2s;
}

__device__ __forceinline__ float sig32(float z) {
  const float e32 = (float)exp(-(double)z);
  return 1.0f / __fadd_rn(1.0f, e32);
}
__device__ __forceinline__ float tanh32f(float z) { return (float)tanh((double)z); }

__device__ __forceinline__ u64 packvc(float v, unsigned col) {
  unsigned u = __float_as_uint(v);
  u = (u & 0x80000000u) ? ~u : (u | 0x80000000u);
  return ((u64)u << 32) | (u64)(0xFFFFFFFFu - col);
}
__device__ __forceinline__ u64 umax64(u64 a, u64 b) { return a > b ? a : b; }

__device__ __forceinline__ size_t faddr(int k, int row) {
  return (size_t)(((k >> 5) * 2 + (row >> 4)) * 512 +
                  (16 * ((k >> 3) & 3) + (row & 15)) * 8 + (k & 7));
}

// ---------------- param structs ----------------

struct MainP {
  const float* emb;
  const float* bias[4];
  const float* fcb;
  const float* hini[4];
  const float* cini[4];
  const f16* WfH[4];
  const f16* WfL[4];
  const f16* fcH;
  const f16* fcLc;     // column-major lo plane [32000][1024]
  const float* shat;   // [256][1024]
  f16* axh[5];
  f16* axl[5];
  f16* axm[5];
  u64* top;
  unsigned* bar;
  float* out;
};

// ---------------- flat parallel-poll grid barrier ----------------
// Every block release-stores flag[blk] = gen (flags 16B apart). Then threads
// 0..255 EACH spin on one flag in parallel (a wave covers 64 flags with one
// vector load per iteration); __syncthreads is the AND; one acquire fence.
// No leader, no serial chain of remote probes (the r5/r11 barriers serialized
// ~32-40 cross-XCD probes per barrier). gen is monotone; '>=' makes a block
// racing ahead to barrier N+1 harmless.

__device__ __forceinline__ void grid_bar4(unsigned* bar, int blk, unsigned gen) {
  __syncthreads();
  if (threadIdx.x == 0)
    __hip_atomic_store(bar + blk * 4, gen, __ATOMIC_RELEASE, __HIP_MEMORY_SCOPE_AGENT);
  if (threadIdx.x < 256) {
    const unsigned* f = bar + threadIdx.x * 4;
    while (__hip_atomic_load(f, __ATOMIC_RELAXED, __HIP_MEMORY_SCOPE_AGENT) < gen)
      __builtin_amdgcn_s_sleep(1);
  }
  __syncthreads();
  __builtin_amdgcn_fence(__ATOMIC_ACQUIRE, "agent");
}

// ---------------- prep kernels (unchanged from r8/r9) ----------------

__global__ __launch_bounds__(256) void prep_lstm(const float* Wx, const float* Wh,
                                                 int Kx, int CH, f16* dh, f16* dl) {
  const int id = blockIdx.x * 256 + threadIdx.x;
  const int lane = id & 63;
  const int cw = id >> 6;
  const int tile = cw / CH;
  if (tile >= 256) return;
  const int chunk = cw - tile * CH;
  const int n16 = lane & 15, qq = lane >> 4;
  const int col = 1024 * (n16 >> 2) + 4 * tile + (n16 & 3);
  const int kb = chunk * 32 + 8 * qq;
  f16x8 hv, lv;
#pragma unroll
  for (int e = 0; e < 8; ++e) {
    const int k = kb + e;
    const float wv = (k < Kx) ? Wx[(size_t)k * 4096 + col] : Wh[(size_t)(k - Kx) * 4096 + col];
    f16 h, l;
    split2(wv, h, l);
    hv[e] = h; lv[e] = l;
  }
  const size_t d = ((size_t)cw * 64 + lane) * 8;
  *(f16x8*)(dh + d) = hv;
  *(f16x8*)(dl + d) = lv;
}

__global__ __launch_bounds__(256) void prep_fc(const float* fcW, f16* dh) {
  const int id = blockIdx.x * 256 + threadIdx.x;
  const int lane = id & 63;
  const int cw = id >> 6;
  const int chunk = cw & 31;
  const int stb = cw >> 5;
  const int st = stb & 7, blk = stb >> 3;
  if (blk >= 256) return;
  const int n16 = lane & 15, qq = lane >> 4;
  int cl = st * 16 + n16;
  if (cl > 124) cl = 124;
  const int col = 125 * blk + cl;
  const int kb = chunk * 32 + 8 * qq;
  f16x8 hv;
#pragma unroll
  for (int e = 0; e < 8; ++e) {
    const float wv = fcW[(size_t)(kb + e) * 32000 + col];
    f16 h, l;
    split2(wv, h, l);
    hv[e] = h; (void)l;
  }
  const size_t d = ((size_t)cw * 64 + lane) * 8;
  *(f16x8*)(dh + d) = hv;
}

__global__ __launch_bounds__(256) void prep_fclT(const float* fcW, f16* fcLc) {
  const int col0 = blockIdx.x * 64;
  const int tid = threadIdx.x;
  __shared__ float lds[64][65];
  for (int pass = 0; pass < 16; ++pass) {
    const int kbase = pass * 64;
#pragma unroll
    for (int rr = 0; rr < 16; ++rr) {
      const int kk = rr * 4 + (tid >> 6);
      lds[kk][tid & 63] = fcW[(size_t)(kbase + kk) * 32000 + col0 + (tid & 63)];
    }
    __syncthreads();
    {
      const int col = tid >> 2, qr = tid & 3;
      f16x8 v0, v1;
#pragma unroll
      for (int i = 0; i < 8; ++i) {
        f16 h, l;
        split2(lds[qr * 16 + i][col], h, l);
        v0[i] = l;
      }
#pragma unroll
      for (int i = 0; i < 8; ++i) {
        f16 h, l;
        split2(lds[qr * 16 + 8 + i][col], h, l);
        v1[i] = l;
      }
      const size_t d = (size_t)(col0 + col) * 1024 + kbase + qr * 16;
      *(f16x8*)(fcLc + d) = v0;
      *(f16x8*)(fcLc + d + 8) = v1;
    }
    __syncthreads();
  }
}

__global__ __launch_bounds__(256) void prep_shat(const float* fcW, float* shat) {
  const int id = blockIdx.x * 256 + threadIdx.x;
  if (id >= 256 * 1024) return;
  const int blk = id >> 10, k = id & 1023;
  const float* src = fcW + (size_t)k * 32000 + 125 * blk;
  float s = 0.f;
  for (int c = 0; c < 125; ++c) {
    f16 h, l;
    split2(src[c], h, l);
    s = fmaxf(s, __builtin_fabsf((float)l));
  }
  shat[id] = s;
}

__global__ void ws_sentinel(float* out) {
  if (blockIdx.x == 0 && threadIdx.x == 0) out[0] = 1.0e9f;
}

// ---------------- main persistent kernel (r9 body + parallel-poll barrier) --

__global__ __launch_bounds__(NTHR, 2) void lstm_main(MainP p) {
  const int blk = blockIdx.x;
  const int tid = threadIdx.x;
  const int lane = tid & 63;
  const int w = tid >> 6;  // 0..7
  const int q = lane >> 4;
  const int n16 = lane & 15;

  __shared__ float zpart[8][2][32][16];   // 32 KB
  __shared__ float fcpart[2][32][128];    // 32 KB ([1]=pre, [0]=z)
  __shared__ float zred[32][16];
  __shared__ float rmaxs[32][16];
  __shared__ float epart[32][16];
  __shared__ float rowmax[32];
  __shared__ float erow[32];
  __shared__ float cst[4][32][4];
  __shared__ f16 hs_h[32][4], hs_l[32][4], hs_m[32][4];
  __shared__ int tokS[32];
  __shared__ u64 redu[32][16];
  __shared__ u64 redu2[32];
  __shared__ int wl[4000];
  __shared__ unsigned cand[32][4];
  __shared__ int wcount;

  unsigned genc = 0;

  // ---- persistent register weights: layers 1 and 2 ----
  f16x8 w1h[8], w1l[8], w2h[8], w2l[8];
#pragma unroll
  for (int sl = 0; sl < 8; ++sl) {
    const size_t wo = ((size_t)(blk * 64 + w * 8 + sl) * 64 + lane) * 8;
    w1h[sl] = *(const f16x8*)(p.WfH[1] + wo);
    w1l[sl] = *(const f16x8*)(p.WfL[1] + wo);
    w2h[sl] = *(const f16x8*)(p.WfH[2] + wo);
    w2l[sl] = *(const f16x8*)(p.WfL[2] + wo);
  }

  // ---- init state ----
  {
    const int i = tid;  // 512 = 4*32*4
    const int l = i >> 7, b = (i >> 2) & 31, j = i & 3;
    cst[l][b][j] = p.cini[l][b * 1024 + 4 * blk + j];
    f16 hh, ll, mm;
    split3(p.hini[l][b * 1024 + 4 * blk + j], hh, ll, mm);
    const int kp = (l == 0) ? (4 * blk + j) : (1024 + 4 * blk + j);
    const size_t a = faddr(kp, b);
    p.axh[l][a] = hh;
    p.axl[l][a] = ll;
    p.axm[l][a] = mm;
  }
  grid_bar4(p.bar, blk, ++genc);

  auto layer_tail = [&](int l, const float* bias, f16* dh, f16* dl, f16* dm) {
    __syncthreads();
    {
      const int row = tid >> 4, c = tid & 15;
      double A = 0.0, B = 0.0;
#pragma unroll
      for (int w2 = 0; w2 < 8; ++w2) {
        A += (double)zpart[w2][0][row][c];
        B += (double)zpart[w2][1][row][c];
      }
      zred[row][c] = __fadd_rn(__fadd_rn((float)A, (float)B),
                               bias[1024 * (c >> 2) + 4 * blk + (c & 3)]);
    }
    __syncthreads();
    if (tid < 128) {
      const int b = tid >> 2, j = tid & 3;
      const float zi = zred[b][j], zf = zred[b][4 + j], zg = zred[b][8 + j], zo = zred[b][12 + j];
      const float i_ = sig32(zi);
      const float f_ = sig32(zf);
      const float g_ = tanh32f(zg);
      const float o_ = sig32(zo);
      const float c_ = __fadd_rn(__fmul_rn(f_, cst[l][b][j]), __fmul_rn(i_, g_));
      cst[l][b][j] = c_;
      const float h_ = __fmul_rn(o_, tanh32f(c_));
      f16 hh, ll, mm;
      split3(h_, hh, ll, mm);
      hs_h[b][j] = hh; hs_l[b][j] = ll; hs_m[b][j] = mm;
      const size_t a = faddr(4 * blk + j, b);
      dh[a] = hh; dl[a] = ll; dm[a] = mm;
    }
  };

  // resident-weight LSTM layer (layers 1,2): chunk = w*8+sl, bucket A iff w<4
  auto lstm_layer_regs = [&](const f16x8 (&WH)[8], const f16x8 (&WL)[8],
                             const f16* axh_, const f16* axl_, const f16* axm_) {
    double zdA0[4] = {0,0,0,0}, zdA1[4] = {0,0,0,0};
    double zdB0[4] = {0,0,0,0}, zdB1[4] = {0,0,0,0};
    const f32x4 zz = {0.f, 0.f, 0.f, 0.f};
#pragma unroll
    for (int sl = 0; sl < 8; ++sl) {
      const int chunk = w * 8 + sl;
      const f16x8 bh = WH[sl];
      const f16x8 bl = WL[sl];
      const size_t b0 = (size_t)(chunk * 2) * 512 + lane * 8;
      const f16x8 ah0 = *(const f16x8*)(axh_ + b0);
      const f16x8 al0 = *(const f16x8*)(axl_ + b0);
      const f16x8 am0 = *(const f16x8*)(axm_ + b0);
      const f16x8 ah1 = *(const f16x8*)(axh_ + b0 + 512);
      const f16x8 al1 = *(const f16x8*)(axl_ + b0 + 512);
      const f16x8 am1 = *(const f16x8*)(axm_ + b0 + 512);
      f32x4 t00 = __builtin_amdgcn_mfma_f32_16x16x32_f16(ah0, bh, zz, 0, 0, 0);
      f32x4 t10 = __builtin_amdgcn_mfma_f32_16x16x32_f16(ah0, bl, zz, 0, 0, 0);
      t10 = __builtin_amdgcn_mfma_f32_16x16x32_f16(al0, bh, t10, 0, 0, 0);
      f32x4 t20 = __builtin_amdgcn_mfma_f32_16x16x32_f16(al0, bl, zz, 0, 0, 0);
      t20 = __builtin_amdgcn_mfma_f32_16x16x32_f16(am0, bh, t20, 0, 0, 0);
      f32x4 t01 = __builtin_amdgcn_mfma_f32_16x16x32_f16(ah1, bh, zz, 0, 0, 0);
      f32x4 t11 = __builtin_amdgcn_mfma_f32_16x16x32_f16(ah1, bl, zz, 0, 0, 0);
      t11 = __builtin_amdgcn_mfma_f32_16x16x32_f16(al1, bh, t11, 0, 0, 0);
      f32x4 t21 = __builtin_amdgcn_mfma_f32_16x16x32_f16(al1, bl, zz, 0, 0, 0);
      t21 = __builtin_amdgcn_mfma_f32_16x16x32_f16(am1, bh, t21, 0, 0, 0);
      if (w < 4) {
#pragma unroll
        for (int r = 0; r < 4; ++r) {
          zdA0[r] += (double)t00[r] + (double)t10[r] * 0x1p-11 + (double)t20[r] * 0x1p-22;
          zdA1[r] += (double)t01[r] + (double)t11[r] * 0x1p-11 + (double)t21[r] * 0x1p-22;
        }
      } else {
#pragma unroll
        for (int r = 0; r < 4; ++r) {
          zdB0[r] += (double)t00[r] + (double)t10[r] * 0x1p-11 + (double)t20[r] * 0x1p-22;
          zdB1[r] += (double)t01[r] + (double)t11[r] * 0x1p-11 + (double)t21[r] * 0x1p-22;
        }
      }
    }
#pragma unroll
    for (int r = 0; r < 4; ++r) {
      zpart[w][0][4 * q + r][n16] = (float)zdA0[r];
      zpart[w][0][16 + 4 * q + r][n16] = (float)zdA1[r];
      zpart[w][1][4 * q + r][n16] = (float)zdB0[r];
      zpart[w][1][16 + 4 * q + r][n16] = (float)zdB1[r];
    }
  };

  for (int t = 0; t < 128; ++t) {
    // ========== PHASE A: decide token ==========
    if (t == 0) {
      if (tid < 32) tokS[tid] = 1;  // START
    } else {
      {
        const int row = tid >> 4, seg = tid & 15;
        const u64* tr = p.top + row * 256 + seg * 16;
        u64 m = 0;
#pragma unroll
        for (int e = 0; e < 16; ++e) m = umax64(m, tr[e]);
        redu[row][seg] = m;
      }
      __syncthreads();
      if (tid < 32) {
        u64 mm = redu[tid][0];
#pragma unroll
        for (int s2 = 1; s2 < 16; ++s2) mm = umax64(mm, redu[tid][s2]);
        const int tok = (int)(0xFFFFFFFFu - (unsigned)(mm & 0xFFFFFFFFull));
        tokS[tid] = tok;
        if (blk == tid)
          p.out[(size_t)32 * 128 * 32000 + (size_t)tid * 128 + (t - 1)] = (float)tok;
      }
    }
    __syncthreads();

    // ========== layer 0: streamed, 6 chunks/wave, chunk=w*6+gg*3+s2 ==========
    {
      double zdA0[4] = {0,0,0,0}, zdA1[4] = {0,0,0,0};
      double zdB0[4] = {0,0,0,0}, zdB1[4] = {0,0,0,0};
      const f32x4 zz = {0.f, 0.f, 0.f, 0.f};
      for (int gg = 0; gg < 2; ++gg) {
        f16x8 WB[6];
#pragma unroll
        for (int s2 = 0; s2 < 3; ++s2) {
          const int chunk = w * 6 + gg * 3 + s2;
          const size_t wo = ((size_t)(blk * 48 + chunk) * 64 + lane) * 8;
          WB[s2 * 2] = *(const f16x8*)(p.WfH[0] + wo);
          WB[s2 * 2 + 1] = *(const f16x8*)(p.WfL[0] + wo);
        }
#pragma unroll
        for (int s2 = 0; s2 < 3; ++s2) {
          const int chunk = w * 6 + gg * 3 + s2;
          const int k0 = chunk * 32 + 8 * q;
          const f16x8 bh = WB[s2 * 2];
          const f16x8 bl = WB[s2 * 2 + 1];
          f16x8 ah0, al0, am0, ah1, al1, am1;
          if (chunk < 16) {
            {
              const float* ep = p.emb + (size_t)tokS[n16] * 512 + k0;
              const float4 v0 = *(const float4*)ep;
              const float4 v1 = *(const float4*)(ep + 4);
              const float vv[8] = {v0.x, v0.y, v0.z, v0.w, v1.x, v1.y, v1.z, v1.w};
#pragma unroll
              for (int e = 0; e < 8; ++e) { f16 a,b,c; split3(vv[e],a,b,c); ah0[e]=a; al0[e]=b; am0[e]=c; }
            }
            {
              const float* ep = p.emb + (size_t)tokS[16 + n16] * 512 + k0;
              const float4 v0 = *(const float4*)ep;
              const float4 v1 = *(const float4*)(ep + 4);
              const float vv[8] = {v0.x, v0.y, v0.z, v0.w, v1.x, v1.y, v1.z, v1.w};
#pragma unroll
              for (int e = 0; e < 8; ++e) { f16 a,b,c; split3(vv[e],a,b,c); ah1[e]=a; al1[e]=b; am1[e]=c; }
            }
          } else {
            const int cs = chunk - 16;
            const size_t b0 = (size_t)(cs * 2) * 512 + lane * 8;
            ah0 = *(const f16x8*)(p.axh[0] + b0);
            al0 = *(const f16x8*)(p.axl[0] + b0);
            am0 = *(const f16x8*)(p.axm[0] + b0);
            ah1 = *(const f16x8*)(p.axh[0] + b0 + 512);
            al1 = *(const f16x8*)(p.axl[0] + b0 + 512);
            am1 = *(const f16x8*)(p.axm[0] + b0 + 512);
          }
          f32x4 t00 = __builtin_amdgcn_mfma_f32_16x16x32_f16(ah0, bh, zz, 0, 0, 0);
          f32x4 t10 = __builtin_amdgcn_mfma_f32_16x16x32_f16(ah0, bl, zz, 0, 0, 0);
          t10 = __builtin_amdgcn_mfma_f32_16x16x32_f16(al0, bh, t10, 0, 0, 0);
          f32x4 t20 = __builtin_amdgcn_mfma_f32_16x16x32_f16(al0, bl, zz, 0, 0, 0);
          t20 = __builtin_amdgcn_mfma_f32_16x16x32_f16(am0, bh, t20, 0, 0, 0);
          f32x4 t01 = __builtin_amdgcn_mfma_f32_16x16x32_f16(ah1, bh, zz, 0, 0, 0);
          f32x4 t11 = __builtin_amdgcn_mfma_f32_16x16x32_f16(ah1, bl, zz, 0, 0, 0);
          t11 = __builtin_amdgcn_mfma_f32_16x16x32_f16(al1, bh, t11, 0, 0, 0);
          f32x4 t21 = __builtin_amdgcn_mfma_f32_16x16x32_f16(al1, bl, zz, 0, 0, 0);
          t21 = __builtin_amdgcn_mfma_f32_16x16x32_f16(am1, bh, t21, 0, 0, 0);
          if (chunk < 16) {
#pragma unroll
            for (int r = 0; r < 4; ++r) {
              zdA0[r] += (double)t00[r] + (double)t10[r] * 0x1p-11 + (double)t20[r] * 0x1p-22;
              zdA1[r] += (double)t01[r] + (double)t11[r] * 0x1p-11 + (double)t21[r] * 0x1p-22;
            }
          } else {
#pragma unroll
            for (int r = 0; r < 4; ++r) {
              zdB0[r] += (double)t00[r] + (double)t10[r] * 0x1p-11 + (double)t20[r] * 0x1p-22;
              zdB1[r] += (double)t01[r] + (double)t11[r] * 0x1p-11 + (double)t21[r] * 0x1p-22;
            }
          }
        }
      }
#pragma unroll
      for (int r = 0; r < 4; ++r) {
        zpart[w][0][4 * q + r][n16] = (float)zdA0[r];
        zpart[w][0][16 + 4 * q + r][n16] = (float)zdA1[r];
        zpart[w][1][4 * q + r][n16] = (float)zdB0[r];
        zpart[w][1][16 + 4 * q + r][n16] = (float)zdB1[r];
      }
    }
    layer_tail(0, p.bias[0], p.axh[1], p.axl[1], p.axm[1]);
    grid_bar4(p.bar, blk, ++genc);

    // ========== layer 1: register weights ==========
    if (tid < 128) {
      const int b = tid >> 2, j = tid & 3;
      const size_t a = faddr(4 * blk + j, b);
      p.axh[0][a] = hs_h[b][j];
      p.axl[0][a] = hs_l[b][j];
      p.axm[0][a] = hs_m[b][j];
    }
    lstm_layer_regs(w1h, w1l, p.axh[1], p.axl[1], p.axm[1]);
    layer_tail(1, p.bias[1], p.axh[2], p.axl[2], p.axm[2]);
    grid_bar4(p.bar, blk, ++genc);

    // ========== layer 2: register weights ==========
    if (tid < 128) {
      const int b = tid >> 2, j = tid & 3;
      const size_t a = faddr(1024 + 4 * blk + j, b);
      p.axh[1][a] = hs_h[b][j];
      p.axl[1][a] = hs_l[b][j];
      p.axm[1][a] = hs_m[b][j];
    }
    lstm_layer_regs(w2h, w2l, p.axh[2], p.axl[2], p.axm[2]);
    layer_tail(2, p.bias[2], p.axh[3], p.axl[3], p.axm[3]);
    grid_bar4(p.bar, blk, ++genc);

    // ========== layer 3: streamed, chunk=w*8+gg*4+s2 ==========
    if (tid < 128) {
      const int b = tid >> 2, j = tid & 3;
      const size_t a = faddr(1024 + 4 * blk + j, b);
      p.axh[2][a] = hs_h[b][j];
      p.axl[2][a] = hs_l[b][j];
      p.axm[2][a] = hs_m[b][j];
    }
    {
      double zdA0[4] = {0,0,0,0}, zdA1[4] = {0,0,0,0};
      double zdB0[4] = {0,0,0,0}, zdB1[4] = {0,0,0,0};
      const f16* axh_ = p.axh[3];
      const f16* axl_ = p.axl[3];
      const f16* axm_ = p.axm[3];
      const f32x4 zz = {0.f, 0.f, 0.f, 0.f};
      for (int gg = 0; gg < 2; ++gg) {
        f16x8 WB[8];
#pragma unroll
        for (int s2 = 0; s2 < 4; ++s2) {
          const int chunk = w * 8 + gg * 4 + s2;
          const size_t wo = ((size_t)(blk * 64 + chunk) * 64 + lane) * 8;
          WB[s2 * 2] = *(const f16x8*)(p.WfH[3] + wo);
          WB[s2 * 2 + 1] = *(const f16x8*)(p.WfL[3] + wo);
        }
#pragma unroll
        for (int s2 = 0; s2 < 4; ++s2) {
          const int chunk = w * 8 + gg * 4 + s2;
          const f16x8 bh = WB[s2 * 2];
          const f16x8 bl = WB[s2 * 2 + 1];
          const size_t b0 = (size_t)(chunk * 2) * 512 + lane * 8;
          const f16x8 ah0 = *(const f16x8*)(axh_ + b0);
          const f16x8 al0 = *(const f16x8*)(axl_ + b0);
          const f16x8 am0 = *(const f16x8*)(axm_ + b0);
          const f16x8 ah1 = *(const f16x8*)(axh_ + b0 + 512);
          const f16x8 al1 = *(const f16x8*)(axl_ + b0 + 512);
          const f16x8 am1 = *(const f16x8*)(axm_ + b0 + 512);
          f32x4 t00 = __builtin_amdgcn_mfma_f32_16x16x32_f16(ah0, bh, zz, 0, 0, 0);
          f32x4 t10 = __builtin_amdgcn_mfma_f32_16x16x32_f16(ah0, bl, zz, 0, 0, 0);
          t10 = __builtin_amdgcn_mfma_f32_16x16x32_f16(al0, bh, t10, 0, 0, 0);
          f32x4 t20 = __builtin_amdgcn_mfma_f32_16x16x32_f16(al0, bl, zz, 0, 0, 0);
          t20 = __builtin_amdgcn_mfma_f32_16x16x32_f16(am0, bh, t20, 0, 0, 0);
          f32x4 t01 = __builtin_amdgcn_mfma_f32_16x16x32_f16(ah1, bh, zz, 0, 0, 0);
          f32x4 t11 = __builtin_amdgcn_mfma_f32_16x16x32_f16(ah1, bl, zz, 0, 0, 0);
          t11 = __builtin_amdgcn_mfma_f32_16x16x32_f16(al1, bh, t11, 0, 0, 0);
          f32x4 t21 = __builtin_amdgcn_mfma_f32_16x16x32_f16(al1, bl, zz, 0, 0, 0);
          t21 = __builtin_amdgcn_mfma_f32_16x16x32_f16(am1, bh, t21, 0, 0, 0);
          if (w < 4) {
#pragma unroll
            for (int r = 0; r < 4; ++r) {
              zdA0[r] += (double)t00[r] + (double)t10[r] * 0x1p-11 + (double)t20[r] * 0x1p-22;
              zdA1[r] += (double)t01[r] + (double)t11[r] * 0x1p-11 + (double)t21[r] * 0x1p-22;
            }
          } else {
#pragma unroll
            for (int r = 0; r < 4; ++r) {
              zdB0[r] += (double)t00[r] + (double)t10[r] * 0x1p-11 + (double)t20[r] * 0x1p-22;
              zdB1[r] += (double)t01[r] + (double)t11[r] * 0x1p-11 + (double)t21[r] * 0x1p-22;
            }
          }
        }
      }
#pragma unroll
      for (int r = 0; r < 4; ++r) {
        zpart[w][0][4 * q + r][n16] = (float)zdA0[r];
        zpart[w][0][16 + 4 * q + r][n16] = (float)zdA1[r];
        zpart[w][1][4 * q + r][n16] = (float)zdB0[r];
        zpart[w][1][16 + 4 * q + r][n16] = (float)zdB1[r];
      }
    }
    layer_tail(3, p.bias[3], p.axh[4], p.axl[4], p.axm[4]);
    grid_bar4(p.bar, blk, ++genc);

    // ========== PHASE E: FC hi-only + refinement ==========
    if (tid < 128) {
      const int b = tid >> 2, j = tid & 3;
      const size_t a = faddr(1024 + 4 * blk + j, b);
      p.axh[3][a] = hs_h[b][j];
      p.axl[3][a] = hs_l[b][j];
      p.axm[3][a] = hs_m[b][j];
    }
    if (tid < 32) redu2[tid] = 0ull;
    if (tid < 128) cand[tid >> 2][tid & 3] = 0u;
    if (tid == 0) wcount = 0;
    {
      const int st = w;
      double Ld0[4] = {0,0,0,0}, Ld1[4] = {0,0,0,0};
      const f32x4 zz = {0.f, 0.f, 0.f, 0.f};
      for (int g = 0; g < 4; ++g) {
        f16x8 FB[8];
#pragma unroll
        for (int i = 0; i < 8; ++i) {
          const int chunk = g * 8 + i;
          FB[i] = *(const f16x8*)(p.fcH + (((size_t)(blk * 8 + st) * 32 + chunk) * 64 + lane) * 8);
        }
#pragma unroll
        for (int i = 0; i < 8; ++i) {
          const int chunk = g * 8 + i;
          const size_t ab = (size_t)(chunk * 2) * 512 + lane * 8;
          const f16x8 ah0 = *(const f16x8*)(p.axh[4] + ab);
          const f16x8 al0 = *(const f16x8*)(p.axl[4] + ab);
          const f16x8 am0 = *(const f16x8*)(p.axm[4] + ab);
          const f16x8 ah1 = *(const f16x8*)(p.axh[4] + ab + 512);
          const f16x8 al1 = *(const f16x8*)(p.axl[4] + ab + 512);
          const f16x8 am1 = *(const f16x8*)(p.axm[4] + ab + 512);
          const f16x8 bh = FB[i];
          f32x4 t00 = __builtin_amdgcn_mfma_f32_16x16x32_f16(ah0, bh, zz, 0, 0, 0);
          f32x4 t10 = __builtin_amdgcn_mfma_f32_16x16x32_f16(al0, bh, zz, 0, 0, 0);
          f32x4 t20 = __builtin_amdgcn_mfma_f32_16x16x32_f16(am0, bh, zz, 0, 0, 0);
          f32x4 t01 = __builtin_amdgcn_mfma_f32_16x16x32_f16(ah1, bh, zz, 0, 0, 0);
          f32x4 t11 = __builtin_amdgcn_mfma_f32_16x16x32_f16(al1, bh, zz, 0, 0, 0);
          f32x4 t21 = __builtin_amdgcn_mfma_f32_16x16x32_f16(am1, bh, zz, 0, 0, 0);
#pragma unroll
          for (int r = 0; r < 4; ++r) {
            Ld0[r] += (double)t00[r] + (double)t10[r] * 0x1p-11 + (double)t20[r] * 0x1p-22;
            Ld1[r] += (double)t01[r] + (double)t11[r] * 0x1p-11 + (double)t21[r] * 0x1p-22;
          }
        }
      }
#pragma unroll
      for (int r = 0; r < 4; ++r) {
        fcpart[1][4 * q + r][st * 16 + n16] = (float)Ld0[r];
        fcpart[1][16 + 4 * q + r][st * 16 + n16] = (float)Ld1[r];
      }
    }
    __syncthreads();
    {
      const int row = tid >> 4, cg = tid & 15;
#pragma unroll
      for (int cc = 0; cc < 8; ++cc) {
        const int c = cg * 8 + cc;
        if (c < 125) {
          const float pre = fcpart[1][row][c];
          fcpart[0][row][c] = __fadd_rn(pre, p.fcb[125 * blk + c]);
        }
      }
      const int seg = cg;
      const float* sh = p.shat + (size_t)blk * 1024 + seg * 64;
      float s = 0.f;
#pragma unroll 8
      for (int i = 0; i < 64; ++i) {
        const float av = __builtin_fabsf((float)p.axh[4][faddr(seg * 64 + i, row)]) + 1e-5f;
        s += av * sh[i];
      }
      epart[row][seg] = s;
    }
    __syncthreads();
    {
      const int row = tid >> 4, cg = tid & 15;
      float m = -3.4e38f;
#pragma unroll
      for (int cc = 0; cc < 8; ++cc) {
        const int c = cg * 8 + cc;
        if (c < 125) m = fmaxf(m, fcpart[0][row][c]);
      }
      rmaxs[row][cg] = m;
    }
    __syncthreads();
    if (tid < 32) {
      float m = rmaxs[tid][0];
      float e = epart[tid][0];
#pragma unroll
      for (int s2 = 1; s2 < 16; ++s2) { m = fmaxf(m, rmaxs[tid][s2]); e += epart[tid][s2]; }
      rowmax[tid] = m;
      erow[tid] = 2.0f * (e * (1.0f / 2048.0f)) * 1.02f + 2e-5f;
    }
    __syncthreads();
    for (int idx = tid; idx < 32 * 128; idx += NTHR) {
      const int row = idx >> 7, c = idx & 127;
      if (c < 125) {
        if (fcpart[0][row][c] >= rowmax[row] - erow[row]) {
          const int pos = atomicAdd(&wcount, 1);
          wl[pos] = (row << 8) | c;
          atomicOr(&cand[row][c >> 5], 1u << (c & 31));
        }
      }
    }
    __syncthreads();
    if (w < 4) {
      const int row = tid >> 3, cg = tid & 7;
      float* orow = p.out + (size_t)row * (128 * 32000) + (size_t)t * 32000 + 125 * blk;
#pragma unroll
      for (int cc = 0; cc < 16; ++cc) {
        const int c = cg * 16 + cc;
        if (c < 125 && !((cand[row][c >> 5] >> (c & 31)) & 1u))
          __builtin_nontemporal_store(fcpart[0][row][c], orow + c);
      }
    } else {
      const int wcnt = wcount;
      for (int i = w - 4; i < wcnt; i += 4) {
        const int ent = wl[i];
        const int row = ent >> 8, cl = ent & 255;
        const int kb = lane * 16;
        const f16x8 A0h = *(const f16x8*)(p.axh[4] + faddr(kb, row));
        const f16x8 A0l = *(const f16x8*)(p.axl[4] + faddr(kb, row));
        const f16x8 A0m = *(const f16x8*)(p.axm[4] + faddr(kb, row));
        const f16x8 A1h = *(const f16x8*)(p.axh[4] + faddr(kb + 8, row));
        const f16x8 A1l = *(const f16x8*)(p.axl[4] + faddr(kb + 8, row));
        const f16x8 A1m = *(const f16x8*)(p.axm[4] + faddr(kb + 8, row));
        const f16* Lc = p.fcLc + (size_t)(125 * blk + cl) * 1024 + kb;
        const f16x8 L0 = *(const f16x8*)(Lc);
        const f16x8 L1 = *(const f16x8*)(Lc + 8);
        double d = 0.0;
#pragma unroll
        for (int e = 0; e < 8; ++e) {
          const double a0 = (double)A0h[e] + (double)A0l[e] * 0x1p-11 + (double)A0m[e] * 0x1p-22;
          const double a1 = (double)A1h[e] + (double)A1l[e] * 0x1p-11 + (double)A1m[e] * 0x1p-22;
          d += a0 * (double)L0[e] + a1 * (double)L1[e];
        }
#pragma unroll
        for (int m2 = 32; m2 >= 1; m2 >>= 1) d += __shfl_xor(d, m2, 64);
        if (lane == 0) {
          const float zr = __fadd_rn((float)((double)fcpart[1][row][cl] + d * 0x1p-11),
                                     p.fcb[125 * blk + cl]);
          atomicMax(&redu2[row], packvc(zr, (unsigned)(125 * blk + cl)));
          p.out[(size_t)row * (128 * 32000) + (size_t)t * 32000 + 125 * blk + cl] = zr;
        }
      }
    }
    __syncthreads();
    if (tid < 32) p.top[tid * 256 + blk] = redu2[tid];
    grid_bar4(p.bar, blk, ++genc);
  }

  // tail: token for t = 127
  if (blk < 32) {
    if (tid < 16) {
      const u64* tr = p.top + blk * 256 + tid * 16;
      u64 m = 0;
#pragma unroll
      for (int e = 0; e < 16; ++e) m = umax64(m, tr[e]);
      redu[0][tid] = m;
    }
    __syncthreads();
    if (tid == 0) {
      u64 mm = redu[0][0];
#pragma unroll
      for (int s2 = 1; s2 < 16; ++s2) mm = umax64(mm, redu[0][s2]);
      p.out[(size_t)32 * 128 * 32000 + (size_t)blk * 128 + 127] =
          (float)(0xFFFFFFFFu - (unsigned)(mm & 0xFFFFFFFFull));
    }
  }
}

// ---------------- host ----------------

extern "C" void kernel_launch(void* const* d_in, const int* in_sizes, int n_in,
                              void* d_out, int out_size, void* d_ws, size_t ws_size,
                              hipStream_t stream) {
  (void)in_sizes; (void)n_in; (void)out_size;
  const float* hini[4] = {(const float*)d_in[0], (const float*)d_in[2], (const float*)d_in[4], (const float*)d_in[6]};
  const float* cini[4] = {(const float*)d_in[1], (const float*)d_in[3], (const float*)d_in[5], (const float*)d_in[7]};
  const float* emb = (const float*)d_in[8];
  const float* Wx[4] = {(const float*)d_in[9], (const float*)d_in[12], (const float*)d_in[15], (const float*)d_in[18]};
  const float* Wh[4] = {(const float*)d_in[10], (const float*)d_in[13], (const float*)d_in[16], (const float*)d_in[19]};
  const float* bias[4] = {(const float*)d_in[11], (const float*)d_in[14], (const float*)d_in[17], (const float*)d_in[20]};
  const float* fcW = (const float*)d_in[21];
  const float* fcb = (const float*)d_in[22];

  char* ws = (char*)d_ws;
  size_t off = 0;
  auto take = [&](size_t bytes) -> char* {
    char* r = ws + off;
    off += (bytes + 255) & ~(size_t)255;
    return r;
  };
  f16* WfH[4]; f16* WfL[4];
  WfH[0] = (f16*)take((size_t)256 * 48 * 64 * 8 * 2);
  WfL[0] = (f16*)take((size_t)256 * 48 * 64 * 8 * 2);
  for (int l = 1; l < 4; ++l) {
    WfH[l] = (f16*)take((size_t)256 * 64 * 64 * 8 * 2);
    WfL[l] = (f16*)take((size_t)256 * 64 * 64 * 8 * 2);
  }
  f16* fcH = (f16*)take((size_t)256 * 8 * 32 * 64 * 8 * 2);
  f16* fcLc = (f16*)take((size_t)32000 * 1024 * 2);
  float* shat = (float*)take((size_t)256 * 1024 * 4);
  f16* axh[5]; f16* axl[5]; f16* axm[5];
  const int axK[5] = {1024, 2048, 2048, 2048, 1024};
  for (int l = 0; l < 5; ++l) {
    axh[l] = (f16*)take((size_t)axK[l] * 32 * 2);
    axl[l] = (f16*)take((size_t)axK[l] * 32 * 2);
    axm[l] = (f16*)take((size_t)axK[l] * 32 * 2);
  }
  u64* top = (u64*)take((size_t)32 * 256 * 8);
  unsigned* bar = (unsigned*)take(4096);

  if (off > ws_size) {
    hipLaunchKernelGGL(ws_sentinel, dim3(1), dim3(1), 0, stream, (float*)d_out);
    return;
  }

  hipMemsetAsync(bar, 0, 4096, stream);
  hipLaunchKernelGGL(prep_lstm, dim3(256 * 48 * 64 / 256), dim3(256), 0, stream,
                     Wx[0], Wh[0], 512, 48, WfH[0], WfL[0]);
  for (int l = 1; l < 4; ++l)
    hipLaunchKernelGGL(prep_lstm, dim3(256 * 64 * 64 / 256), dim3(256), 0, stream,
                       Wx[l], Wh[l], 1024, 64, WfH[l], WfL[l]);
  hipLaunchKernelGGL(prep_fc, dim3(256 * 8 * 32 * 64 / 256), dim3(256), 0, stream,
                     fcW, fcH);
  hipLaunchKernelGGL(prep_fclT, dim3(500), dim3(256), 0, stream, fcW, fcLc);
  hipLaunchKernelGGL(prep_shat, dim3(1024), dim3(256), 0, stream, fcW, shat);

  MainP mp;
  mp.emb = emb;
  for (int l = 0; l < 4; ++l) {
    mp.bias[l] = bias[l]; mp.hini[l] = hini[l]; mp.cini[l] = cini[l];
    mp.WfH[l] = WfH[l]; mp.WfL[l] = WfL[l];
  }
  mp.fcb = fcb; mp.fcH = fcH; mp.fcLc = fcLc; mp.shat = shat;
  for (int l = 0; l < 5; ++l) { mp.axh[l] = axh[l]; mp.axl[l] = axl[l]; mp.axm[l] = axm[l]; }
  mp.top = top; mp.bar = bar; mp.out = (float*)d_out;

  void* args[] = {&mp};
  hipLaunchCooperativeKernel((void*)lstm_main, dim3(NBLK), dim3(NTHR), args, 0, stream);
}

// Round 13
// 28364.673 us; speedup vs baseline: 1.2881x; 1.2881x over previous
//
#include <hip/hip_runtime.h>
#include <stdint.h>

#define NBLK 256
#define NTHR 512

typedef _Float16 f16;
typedef _Float16 f16x8 __attribute__((ext_vector_type(8)));
typedef float f32x4 __attribute__((ext_vector_type(4)));
typedef unsigned long long u64;

// ---------------- helpers ----------------

__device__ __forceinline__ void split2(float w, f16& hi, f16& lo) {
  f16 h = (__builtin_fabsf(w) < 6.104e-05f) ? (f16)0.0f : (f16)w;
  hi = h;
  lo = (f16)((w - (float)h) * 2048.0f);
}

__device__ __forceinline__ void split3(float w, f16& h, f16& l, f16& m) {
  const float hf = (__builtin_fabsf(w) < 6.104e-05f) ? 0.0f : (float)(f16)w;
  h = (f16)hf;
  const float r1s = (w - hf) * 2048.0f;
  const float lf = (__builtin_fabsf(r1s) < 6.104e-05f) ? 0.0f : (float)(f16)r1s;
  l = (f16)lf;
  const float r2s = (r1s - lf) * 2048.0f;
  m = (__builtin_fabsf(r2s) < 6.104e-05f) ? (f16)0.0f : (f16)r2s;
}

__device__ __forceinline__ float sig32(float z) {
  const float e32 = (float)exp(-(double)z);
  return 1.0f / __fadd_rn(1.0f, e32);
}
__device__ __forceinline__ float tanh32f(float z) { return (float)tanh((double)z); }

__device__ __forceinline__ u64 packvc(float v, unsigned col) {
  unsigned u = __float_as_uint(v);
  u = (u & 0x80000000u) ? ~u : (u | 0x80000000u);
  return ((u64)u << 32) | (u64)(0xFFFFFFFFu - col);
}
__device__ __forceinline__ u64 umax64(u64 a, u64 b) { return a > b ? a : b; }

__device__ __forceinline__ size_t faddr(int k, int row) {
  return (size_t)(((k >> 5) * 2 + (row >> 4)) * 512 +
                  (16 * ((k >> 3) & 3) + (row & 15)) * 8 + (k & 7));
}

// ---------------- param structs ----------------

struct MainP {
  const float* emb;
  const float* bias[4];
  const float* fcb;
  const float* hini[4];
  const float* cini[4];
  const f16* WfH[4];
  const f16* WfL[4];
  const f16* fcH;
  const f16* fcLc;     // column-major lo plane [32000][1024]
  const float* shat;   // [256][1024]
  f16* axh[5];
  f16* axl[5];
  f16* axm[5];
  u64* top;
  unsigned* bar;
  float* out;
};

// ---------------- central-detection grid barrier ----------------
// Arrival: every block release-stores flag[blk] (16B spacing). Detection: ONLY
// block 0 polls — its 256 threads each watch one flag IN PARALLEL (one fabric
// round per iteration, vs r11's 32 SERIAL probes and r12's 65k polling
// streams). Release: block 0 stores 8 replicated release words; each other
// block polls release[blk&7] (<=32 read-only pollers per line). gen is
// monotone; '>=' makes racing ahead safe.

__device__ __forceinline__ void grid_bar5(unsigned* bar, int blk, unsigned gen) {
  __syncthreads();
  if (threadIdx.x == 0)
    __hip_atomic_store(bar + blk * 4, gen, __ATOMIC_RELEASE, __HIP_MEMORY_SCOPE_AGENT);
  if (blk == 0) {
    if (threadIdx.x < 256) {
      const unsigned* f = bar + threadIdx.x * 4;
      while (__hip_atomic_load(f, __ATOMIC_RELAXED, __HIP_MEMORY_SCOPE_AGENT) < gen)
        __builtin_amdgcn_s_sleep(1);
    }
    __syncthreads();
    __builtin_amdgcn_fence(__ATOMIC_ACQUIRE, "agent");
    if (threadIdx.x < 8)
      __hip_atomic_store(bar + 1024 + threadIdx.x * 16, gen, __ATOMIC_RELEASE,
                         __HIP_MEMORY_SCOPE_AGENT);
  } else {
    if (threadIdx.x == 0) {
      const unsigned* r = bar + 1024 + (blk & 7) * 16;
      while (__hip_atomic_load(r, __ATOMIC_RELAXED, __HIP_MEMORY_SCOPE_AGENT) < gen)
        __builtin_amdgcn_s_sleep(2);
      __builtin_amdgcn_fence(__ATOMIC_ACQUIRE, "agent");
    }
  }
  __syncthreads();
}

// ---------------- prep kernels (unchanged from r8/r9) ----------------

__global__ __launch_bounds__(256) void prep_lstm(const float* Wx, const float* Wh,
                                                 int Kx, int CH, f16* dh, f16* dl) {
  const int id = blockIdx.x * 256 + threadIdx.x;
  const int lane = id & 63;
  const int cw = id >> 6;
  const int tile = cw / CH;
  if (tile >= 256) return;
  const int chunk = cw - tile * CH;
  const int n16 = lane & 15, qq = lane >> 4;
  const int col = 1024 * (n16 >> 2) + 4 * tile + (n16 & 3);
  const int kb = chunk * 32 + 8 * qq;
  f16x8 hv, lv;
#pragma unroll
  for (int e = 0; e < 8; ++e) {
    const int k = kb + e;
    const float wv = (k < Kx) ? Wx[(size_t)k * 4096 + col] : Wh[(size_t)(k - Kx) * 4096 + col];
    f16 h, l;
    split2(wv, h, l);
    hv[e] = h; lv[e] = l;
  }
  const size_t d = ((size_t)cw * 64 + lane) * 8;
  *(f16x8*)(dh + d) = hv;
  *(f16x8*)(dl + d) = lv;
}

__global__ __launch_bounds__(256) void prep_fc(const float* fcW, f16* dh) {
  const int id = blockIdx.x * 256 + threadIdx.x;
  const int lane = id & 63;
  const int cw = id >> 6;
  const int chunk = cw & 31;
  const int stb = cw >> 5;
  const int st = stb & 7, blk = stb >> 3;
  if (blk >= 256) return;
  const int n16 = lane & 15, qq = lane >> 4;
  int cl = st * 16 + n16;
  if (cl > 124) cl = 124;
  const int col = 125 * blk + cl;
  const int kb = chunk * 32 + 8 * qq;
  f16x8 hv;
#pragma unroll
  for (int e = 0; e < 8; ++e) {
    const float wv = fcW[(size_t)(kb + e) * 32000 + col];
    f16 h, l;
    split2(wv, h, l);
    hv[e] = h; (void)l;
  }
  const size_t d = ((size_t)cw * 64 + lane) * 8;
  *(f16x8*)(dh + d) = hv;
}

__global__ __launch_bounds__(256) void prep_fclT(const float* fcW, f16* fcLc) {
  const int col0 = blockIdx.x * 64;
  const int tid = threadIdx.x;
  __shared__ float lds[64][65];
  for (int pass = 0; pass < 16; ++pass) {
    const int kbase = pass * 64;
#pragma unroll
    for (int rr = 0; rr < 16; ++rr) {
      const int kk = rr * 4 + (tid >> 6);
      lds[kk][tid & 63] = fcW[(size_t)(kbase + kk) * 32000 + col0 + (tid & 63)];
    }
    __syncthreads();
    {
      const int col = tid >> 2, qr = tid & 3;
      f16x8 v0, v1;
#pragma unroll
      for (int i = 0; i < 8; ++i) {
        f16 h, l;
        split2(lds[qr * 16 + i][col], h, l);
        v0[i] = l;
      }
#pragma unroll
      for (int i = 0; i < 8; ++i) {
        f16 h, l;
        split2(lds[qr * 16 + 8 + i][col], h, l);
        v1[i] = l;
      }
      const size_t d = (size_t)(col0 + col) * 1024 + kbase + qr * 16;
      *(f16x8*)(fcLc + d) = v0;
      *(f16x8*)(fcLc + d + 8) = v1;
    }
    __syncthreads();
  }
}

__global__ __launch_bounds__(256) void prep_shat(const float* fcW, float* shat) {
  const int id = blockIdx.x * 256 + threadIdx.x;
  if (id >= 256 * 1024) return;
  const int blk = id >> 10, k = id & 1023;
  const float* src = fcW + (size_t)k * 32000 + 125 * blk;
  float s = 0.f;
  for (int c = 0; c < 125; ++c) {
    f16 h, l;
    split2(src[c], h, l);
    s = fmaxf(s, __builtin_fabsf((float)l));
  }
  shat[id] = s;
}

__global__ void ws_sentinel(float* out) {
  if (blockIdx.x == 0 && threadIdx.x == 0) out[0] = 1.0e9f;
}

// ---------------- main persistent kernel (r9 body + central barrier) --------

__global__ __launch_bounds__(NTHR, 2) void lstm_main(MainP p) {
  const int blk = blockIdx.x;
  const int tid = threadIdx.x;
  const int lane = tid & 63;
  const int w = tid >> 6;  // 0..7
  const int q = lane >> 4;
  const int n16 = lane & 15;

  __shared__ float zpart[8][2][32][16];   // 32 KB
  __shared__ float fcpart[2][32][128];    // 32 KB ([1]=pre, [0]=z)
  __shared__ float zred[32][16];
  __shared__ float rmaxs[32][16];
  __shared__ float epart[32][16];
  __shared__ float rowmax[32];
  __shared__ float erow[32];
  __shared__ float cst[4][32][4];
  __shared__ f16 hs_h[32][4], hs_l[32][4], hs_m[32][4];
  __shared__ int tokS[32];
  __shared__ u64 redu[32][16];
  __shared__ u64 redu2[32];
  __shared__ int wl[4000];
  __shared__ unsigned cand[32][4];
  __shared__ int wcount;

  unsigned genc = 0;

  // ---- persistent register weights: layers 1 and 2 ----
  f16x8 w1h[8], w1l[8], w2h[8], w2l[8];
#pragma unroll
  for (int sl = 0; sl < 8; ++sl) {
    const size_t wo = ((size_t)(blk * 64 + w * 8 + sl) * 64 + lane) * 8;
    w1h[sl] = *(const f16x8*)(p.WfH[1] + wo);
    w1l[sl] = *(const f16x8*)(p.WfL[1] + wo);
    w2h[sl] = *(const f16x8*)(p.WfH[2] + wo);
    w2l[sl] = *(const f16x8*)(p.WfL[2] + wo);
  }

  // ---- init state ----
  {
    const int i = tid;  // 512 = 4*32*4
    const int l = i >> 7, b = (i >> 2) & 31, j = i & 3;
    cst[l][b][j] = p.cini[l][b * 1024 + 4 * blk + j];
    f16 hh, ll, mm;
    split3(p.hini[l][b * 1024 + 4 * blk + j], hh, ll, mm);
    const int kp = (l == 0) ? (4 * blk + j) : (1024 + 4 * blk + j);
    const size_t a = faddr(kp, b);
    p.axh[l][a] = hh;
    p.axl[l][a] = ll;
    p.axm[l][a] = mm;
  }
  grid_bar5(p.bar, blk, ++genc);

  auto layer_tail = [&](int l, const float* bias, f16* dh, f16* dl, f16* dm) {
    __syncthreads();
    {
      const int row = tid >> 4, c = tid & 15;
      double A = 0.0, B = 0.0;
#pragma unroll
      for (int w2 = 0; w2 < 8; ++w2) {
        A += (double)zpart[w2][0][row][c];
        B += (double)zpart[w2][1][row][c];
      }
      zred[row][c] = __fadd_rn(__fadd_rn((float)A, (float)B),
                               bias[1024 * (c >> 2) + 4 * blk + (c & 3)]);
    }
    __syncthreads();
    if (tid < 128) {
      const int b = tid >> 2, j = tid & 3;
      const float zi = zred[b][j], zf = zred[b][4 + j], zg = zred[b][8 + j], zo = zred[b][12 + j];
      const float i_ = sig32(zi);
      const float f_ = sig32(zf);
      const float g_ = tanh32f(zg);
      const float o_ = sig32(zo);
      const float c_ = __fadd_rn(__fmul_rn(f_, cst[l][b][j]), __fmul_rn(i_, g_));
      cst[l][b][j] = c_;
      const float h_ = __fmul_rn(o_, tanh32f(c_));
      f16 hh, ll, mm;
      split3(h_, hh, ll, mm);
      hs_h[b][j] = hh; hs_l[b][j] = ll; hs_m[b][j] = mm;
      const size_t a = faddr(4 * blk + j, b);
      dh[a] = hh; dl[a] = ll; dm[a] = mm;
    }
  };

  // resident-weight LSTM layer (layers 1,2): chunk = w*8+sl, bucket A iff w<4
  auto lstm_layer_regs = [&](const f16x8 (&WH)[8], const f16x8 (&WL)[8],
                             const f16* axh_, const f16* axl_, const f16* axm_) {
    double zdA0[4] = {0,0,0,0}, zdA1[4] = {0,0,0,0};
    double zdB0[4] = {0,0,0,0}, zdB1[4] = {0,0,0,0};
    const f32x4 zz = {0.f, 0.f, 0.f, 0.f};
#pragma unroll
    for (int sl = 0; sl < 8; ++sl) {
      const int chunk = w * 8 + sl;
      const f16x8 bh = WH[sl];
      const f16x8 bl = WL[sl];
      const size_t b0 = (size_t)(chunk * 2) * 512 + lane * 8;
      const f16x8 ah0 = *(const f16x8*)(axh_ + b0);
      const f16x8 al0 = *(const f16x8*)(axl_ + b0);
      const f16x8 am0 = *(const f16x8*)(axm_ + b0);
      const f16x8 ah1 = *(const f16x8*)(axh_ + b0 + 512);
      const f16x8 al1 = *(const f16x8*)(axl_ + b0 + 512);
      const f16x8 am1 = *(const f16x8*)(axm_ + b0 + 512);
      f32x4 t00 = __builtin_amdgcn_mfma_f32_16x16x32_f16(ah0, bh, zz, 0, 0, 0);
      f32x4 t10 = __builtin_amdgcn_mfma_f32_16x16x32_f16(ah0, bl, zz, 0, 0, 0);
      t10 = __builtin_amdgcn_mfma_f32_16x16x32_f16(al0, bh, t10, 0, 0, 0);
      f32x4 t20 = __builtin_amdgcn_mfma_f32_16x16x32_f16(al0, bl, zz, 0, 0, 0);
      t20 = __builtin_amdgcn_mfma_f32_16x16x32_f16(am0, bh, t20, 0, 0, 0);
      f32x4 t01 = __builtin_amdgcn_mfma_f32_16x16x32_f16(ah1, bh, zz, 0, 0, 0);
      f32x4 t11 = __builtin_amdgcn_mfma_f32_16x16x32_f16(ah1, bl, zz, 0, 0, 0);
      t11 = __builtin_amdgcn_mfma_f32_16x16x32_f16(al1, bh, t11, 0, 0, 0);
      f32x4 t21 = __builtin_amdgcn_mfma_f32_16x16x32_f16(al1, bl, zz, 0, 0, 0);
      t21 = __builtin_amdgcn_mfma_f32_16x16x32_f16(am1, bh, t21, 0, 0, 0);
      if (w < 4) {
#pragma unroll
        for (int r = 0; r < 4; ++r) {
          zdA0[r] += (double)t00[r] + (double)t10[r] * 0x1p-11 + (double)t20[r] * 0x1p-22;
          zdA1[r] += (double)t01[r] + (double)t11[r] * 0x1p-11 + (double)t21[r] * 0x1p-22;
        }
      } else {
#pragma unroll
        for (int r = 0; r < 4; ++r) {
          zdB0[r] += (double)t00[r] + (double)t10[r] * 0x1p-11 + (double)t20[r] * 0x1p-22;
          zdB1[r] += (double)t01[r] + (double)t11[r] * 0x1p-11 + (double)t21[r] * 0x1p-22;
        }
      }
    }
#pragma unroll
    for (int r = 0; r < 4; ++r) {
      zpart[w][0][4 * q + r][n16] = (float)zdA0[r];
      zpart[w][0][16 + 4 * q + r][n16] = (float)zdA1[r];
      zpart[w][1][4 * q + r][n16] = (float)zdB0[r];
      zpart[w][1][16 + 4 * q + r][n16] = (float)zdB1[r];
    }
  };

  for (int t = 0; t < 128; ++t) {
    // ========== PHASE A: decide token ==========
    if (t == 0) {
      if (tid < 32) tokS[tid] = 1;  // START
    } else {
      {
        const int row = tid >> 4, seg = tid & 15;
        const u64* tr = p.top + row * 256 + seg * 16;
        u64 m = 0;
#pragma unroll
        for (int e = 0; e < 16; ++e) m = umax64(m, tr[e]);
        redu[row][seg] = m;
      }
      __syncthreads();
      if (tid < 32) {
        u64 mm = redu[tid][0];
#pragma unroll
        for (int s2 = 1; s2 < 16; ++s2) mm = umax64(mm, redu[tid][s2]);
        const int tok = (int)(0xFFFFFFFFu - (unsigned)(mm & 0xFFFFFFFFull));
        tokS[tid] = tok;
        if (blk == tid)
          p.out[(size_t)32 * 128 * 32000 + (size_t)tid * 128 + (t - 1)] = (float)tok;
      }
    }
    __syncthreads();

    // ========== layer 0: streamed, 6 chunks/wave, chunk=w*6+gg*3+s2 ==========
    {
      double zdA0[4] = {0,0,0,0}, zdA1[4] = {0,0,0,0};
      double zdB0[4] = {0,0,0,0}, zdB1[4] = {0,0,0,0};
      const f32x4 zz = {0.f, 0.f, 0.f, 0.f};
      for (int gg = 0; gg < 2; ++gg) {
        f16x8 WB[6];
#pragma unroll
        for (int s2 = 0; s2 < 3; ++s2) {
          const int chunk = w * 6 + gg * 3 + s2;
          const size_t wo = ((size_t)(blk * 48 + chunk) * 64 + lane) * 8;
          WB[s2 * 2] = *(const f16x8*)(p.WfH[0] + wo);
          WB[s2 * 2 + 1] = *(const f16x8*)(p.WfL[0] + wo);
        }
#pragma unroll
        for (int s2 = 0; s2 < 3; ++s2) {
          const int chunk = w * 6 + gg * 3 + s2;
          const int k0 = chunk * 32 + 8 * q;
          const f16x8 bh = WB[s2 * 2];
          const f16x8 bl = WB[s2 * 2 + 1];
          f16x8 ah0, al0, am0, ah1, al1, am1;
          if (chunk < 16) {
            {
              const float* ep = p.emb + (size_t)tokS[n16] * 512 + k0;
              const float4 v0 = *(const float4*)ep;
              const float4 v1 = *(const float4*)(ep + 4);
              const float vv[8] = {v0.x, v0.y, v0.z, v0.w, v1.x, v1.y, v1.z, v1.w};
#pragma unroll
              for (int e = 0; e < 8; ++e) { f16 a,b,c; split3(vv[e],a,b,c); ah0[e]=a; al0[e]=b; am0[e]=c; }
            }
            {
              const float* ep = p.emb + (size_t)tokS[16 + n16] * 512 + k0;
              const float4 v0 = *(const float4*)ep;
              const float4 v1 = *(const float4*)(ep + 4);
              const float vv[8] = {v0.x, v0.y, v0.z, v0.w, v1.x, v1.y, v1.z, v1.w};
#pragma unroll
              for (int e = 0; e < 8; ++e) { f16 a,b,c; split3(vv[e],a,b,c); ah1[e]=a; al1[e]=b; am1[e]=c; }
            }
          } else {
            const int cs = chunk - 16;
            const size_t b0 = (size_t)(cs * 2) * 512 + lane * 8;
            ah0 = *(const f16x8*)(p.axh[0] + b0);
            al0 = *(const f16x8*)(p.axl[0] + b0);
            am0 = *(const f16x8*)(p.axm[0] + b0);
            ah1 = *(const f16x8*)(p.axh[0] + b0 + 512);
            al1 = *(const f16x8*)(p.axl[0] + b0 + 512);
            am1 = *(const f16x8*)(p.axm[0] + b0 + 512);
          }
          f32x4 t00 = __builtin_amdgcn_mfma_f32_16x16x32_f16(ah0, bh, zz, 0, 0, 0);
          f32x4 t10 = __builtin_amdgcn_mfma_f32_16x16x32_f16(ah0, bl, zz, 0, 0, 0);
          t10 = __builtin_amdgcn_mfma_f32_16x16x32_f16(al0, bh, t10, 0, 0, 0);
          f32x4 t20 = __builtin_amdgcn_mfma_f32_16x16x32_f16(al0, bl, zz, 0, 0, 0);
          t20 = __builtin_amdgcn_mfma_f32_16x16x32_f16(am0, bh, t20, 0, 0, 0);
          f32x4 t01 = __builtin_amdgcn_mfma_f32_16x16x32_f16(ah1, bh, zz, 0, 0, 0);
          f32x4 t11 = __builtin_amdgcn_mfma_f32_16x16x32_f16(ah1, bl, zz, 0, 0, 0);
          t11 = __builtin_amdgcn_mfma_f32_16x16x32_f16(al1, bh, t11, 0, 0, 0);
          f32x4 t21 = __builtin_amdgcn_mfma_f32_16x16x32_f16(al1, bl, zz, 0, 0, 0);
          t21 = __builtin_amdgcn_mfma_f32_16x16x32_f16(am1, bh, t21, 0, 0, 0);
          if (chunk < 16) {
#pragma unroll
            for (int r = 0; r < 4; ++r) {
              zdA0[r] += (double)t00[r] + (double)t10[r] * 0x1p-11 + (double)t20[r] * 0x1p-22;
              zdA1[r] += (double)t01[r] + (double)t11[r] * 0x1p-11 + (double)t21[r] * 0x1p-22;
            }
          } else {
#pragma unroll
            for (int r = 0; r < 4; ++r) {
              zdB0[r] += (double)t00[r] + (double)t10[r] * 0x1p-11 + (double)t20[r] * 0x1p-22;
              zdB1[r] += (double)t01[r] + (double)t11[r] * 0x1p-11 + (double)t21[r] * 0x1p-22;
            }
          }
        }
      }
#pragma unroll
      for (int r = 0; r < 4; ++r) {
        zpart[w][0][4 * q + r][n16] = (float)zdA0[r];
        zpart[w][0][16 + 4 * q + r][n16] = (float)zdA1[r];
        zpart[w][1][4 * q + r][n16] = (float)zdB0[r];
        zpart[w][1][16 + 4 * q + r][n16] = (float)zdB1[r];
      }
    }
    layer_tail(0, p.bias[0], p.axh[1], p.axl[1], p.axm[1]);
    grid_bar5(p.bar, blk, ++genc);

    // ========== layer 1: register weights ==========
    if (tid < 128) {
      const int b = tid >> 2, j = tid & 3;
      const size_t a = faddr(4 * blk + j, b);
      p.axh[0][a] = hs_h[b][j];
      p.axl[0][a] = hs_l[b][j];
      p.axm[0][a] = hs_m[b][j];
    }
    lstm_layer_regs(w1h, w1l, p.axh[1], p.axl[1], p.axm[1]);
    layer_tail(1, p.bias[1], p.axh[2], p.axl[2], p.axm[2]);
    grid_bar5(p.bar, blk, ++genc);

    // ========== layer 2: register weights ==========
    if (tid < 128) {
      const int b = tid >> 2, j = tid & 3;
      const size_t a = faddr(1024 + 4 * blk + j, b);
      p.axh[1][a] = hs_h[b][j];
      p.axl[1][a] = hs_l[b][j];
      p.axm[1][a] = hs_m[b][j];
    }
    lstm_layer_regs(w2h, w2l, p.axh[2], p.axl[2], p.axm[2]);
    layer_tail(2, p.bias[2], p.axh[3], p.axl[3], p.axm[3]);
    grid_bar5(p.bar, blk, ++genc);

    // ========== layer 3: streamed, chunk=w*8+gg*4+s2 ==========
    if (tid < 128) {
      const int b = tid >> 2, j = tid & 3;
      const size_t a = faddr(1024 + 4 * blk + j, b);
      p.axh[2][a] = hs_h[b][j];
      p.axl[2][a] = hs_l[b][j];
      p.axm[2][a] = hs_m[b][j];
    }
    {
      double zdA0[4] = {0,0,0,0}, zdA1[4] = {0,0,0,0};
      double zdB0[4] = {0,0,0,0}, zdB1[4] = {0,0,0,0};
      const f16* axh_ = p.axh[3];
      const f16* axl_ = p.axl[3];
      const f16* axm_ = p.axm[3];
      const f32x4 zz = {0.f, 0.f, 0.f, 0.f};
      for (int gg = 0; gg < 2; ++gg) {
        f16x8 WB[8];
#pragma unroll
        for (int s2 = 0; s2 < 4; ++s2) {
          const int chunk = w * 8 + gg * 4 + s2;
          const size_t wo = ((size_t)(blk * 64 + chunk) * 64 + lane) * 8;
          WB[s2 * 2] = *(const f16x8*)(p.WfH[3] + wo);
          WB[s2 * 2 + 1] = *(const f16x8*)(p.WfL[3] + wo);
        }
#pragma unroll
        for (int s2 = 0; s2 < 4; ++s2) {
          const int chunk = w * 8 + gg * 4 + s2;
          const f16x8 bh = WB[s2 * 2];
          const f16x8 bl = WB[s2 * 2 + 1];
          const size_t b0 = (size_t)(chunk * 2) * 512 + lane * 8;
          const f16x8 ah0 = *(const f16x8*)(axh_ + b0);
          const f16x8 al0 = *(const f16x8*)(axl_ + b0);
          const f16x8 am0 = *(const f16x8*)(axm_ + b0);
          const f16x8 ah1 = *(const f16x8*)(axh_ + b0 + 512);
          const f16x8 al1 = *(const f16x8*)(axl_ + b0 + 512);
          const f16x8 am1 = *(const f16x8*)(axm_ + b0 + 512);
          f32x4 t00 = __builtin_amdgcn_mfma_f32_16x16x32_f16(ah0, bh, zz, 0, 0, 0);
          f32x4 t10 = __builtin_amdgcn_mfma_f32_16x16x32_f16(ah0, bl, zz, 0, 0, 0);
          t10 = __builtin_amdgcn_mfma_f32_16x16x32_f16(al0, bh, t10, 0, 0, 0);
          f32x4 t20 = __builtin_amdgcn_mfma_f32_16x16x32_f16(al0, bl, zz, 0, 0, 0);
          t20 = __builtin_amdgcn_mfma_f32_16x16x32_f16(am0, bh, t20, 0, 0, 0);
          f32x4 t01 = __builtin_amdgcn_mfma_f32_16x16x32_f16(ah1, bh, zz, 0, 0, 0);
          f32x4 t11 = __builtin_amdgcn_mfma_f32_16x16x32_f16(ah1, bl, zz, 0, 0, 0);
          t11 = __builtin_amdgcn_mfma_f32_16x16x32_f16(al1, bh, t11, 0, 0, 0);
          f32x4 t21 = __builtin_amdgcn_mfma_f32_16x16x32_f16(al1, bl, zz, 0, 0, 0);
          t21 = __builtin_amdgcn_mfma_f32_16x16x32_f16(am1, bh, t21, 0, 0, 0);
          if (w < 4) {
#pragma unroll
            for (int r = 0; r < 4; ++r) {
              zdA0[r] += (double)t00[r] + (double)t10[r] * 0x1p-11 + (double)t20[r] * 0x1p-22;
              zdA1[r] += (double)t01[r] + (double)t11[r] * 0x1p-11 + (double)t21[r] * 0x1p-22;
            }
          } else {
#pragma unroll
            for (int r = 0; r < 4; ++r) {
              zdB0[r] += (double)t00[r] + (double)t10[r] * 0x1p-11 + (double)t20[r] * 0x1p-22;
              zdB1[r] += (double)t01[r] + (double)t11[r] * 0x1p-11 + (double)t21[r] * 0x1p-22;
            }
          }
        }
      }
#pragma unroll
      for (int r = 0; r < 4; ++r) {
        zpart[w][0][4 * q + r][n16] = (float)zdA0[r];
        zpart[w][0][16 + 4 * q + r][n16] = (float)zdA1[r];
        zpart[w][1][4 * q + r][n16] = (float)zdB0[r];
        zpart[w][1][16 + 4 * q + r][n16] = (float)zdB1[r];
      }
    }
    layer_tail(3, p.bias[3], p.axh[4], p.axl[4], p.axm[4]);
    grid_bar5(p.bar, blk, ++genc);

    // ========== PHASE E: FC hi-only + refinement ==========
    if (tid < 128) {
      const int b = tid >> 2, j = tid & 3;
      const size_t a = faddr(1024 + 4 * blk + j, b);
      p.axh[3][a] = hs_h[b][j];
      p.axl[3][a] = hs_l[b][j];
      p.axm[3][a] = hs_m[b][j];
    }
    if (tid < 32) redu2[tid] = 0ull;
    if (tid < 128) cand[tid >> 2][tid & 3] = 0u;
    if (tid == 0) wcount = 0;
    {
      const int st = w;
      double Ld0[4] = {0,0,0,0}, Ld1[4] = {0,0,0,0};
      const f32x4 zz = {0.f, 0.f, 0.f, 0.f};
      for (int g = 0; g < 4; ++g) {
        f16x8 FB[8];
#pragma unroll
        for (int i = 0; i < 8; ++i) {
          const int chunk = g * 8 + i;
          FB[i] = *(const f16x8*)(p.fcH + (((size_t)(blk * 8 + st) * 32 + chunk) * 64 + lane) * 8);
        }
#pragma unroll
        for (int i = 0; i < 8; ++i) {
          const int chunk = g * 8 + i;
          const size_t ab = (size_t)(chunk * 2) * 512 + lane * 8;
          const f16x8 ah0 = *(const f16x8*)(p.axh[4] + ab);
          const f16x8 al0 = *(const f16x8*)(p.axl[4] + ab);
          const f16x8 am0 = *(const f16x8*)(p.axm[4] + ab);
          const f16x8 ah1 = *(const f16x8*)(p.axh[4] + ab + 512);
          const f16x8 al1 = *(const f16x8*)(p.axl[4] + ab + 512);
          const f16x8 am1 = *(const f16x8*)(p.axm[4] + ab + 512);
          const f16x8 bh = FB[i];
          f32x4 t00 = __builtin_amdgcn_mfma_f32_16x16x32_f16(ah0, bh, zz, 0, 0, 0);
          f32x4 t10 = __builtin_amdgcn_mfma_f32_16x16x32_f16(al0, bh, zz, 0, 0, 0);
          f32x4 t20 = __builtin_amdgcn_mfma_f32_16x16x32_f16(am0, bh, zz, 0, 0, 0);
          f32x4 t01 = __builtin_amdgcn_mfma_f32_16x16x32_f16(ah1, bh, zz, 0, 0, 0);
          f32x4 t11 = __builtin_amdgcn_mfma_f32_16x16x32_f16(al1, bh, zz, 0, 0, 0);
          f32x4 t21 = __builtin_amdgcn_mfma_f32_16x16x32_f16(am1, bh, zz, 0, 0, 0);
#pragma unroll
          for (int r = 0; r < 4; ++r) {
            Ld0[r] += (double)t00[r] + (double)t10[r] * 0x1p-11 + (double)t20[r] * 0x1p-22;
            Ld1[r] += (double)t01[r] + (double)t11[r] * 0x1p-11 + (double)t21[r] * 0x1p-22;
          }
        }
      }
#pragma unroll
      for (int r = 0; r < 4; ++r) {
        fcpart[1][4 * q + r][st * 16 + n16] = (float)Ld0[r];
        fcpart[1][16 + 4 * q + r][st * 16 + n16] = (float)Ld1[r];
      }
    }
    __syncthreads();
    {
      const int row = tid >> 4, cg = tid & 15;
#pragma unroll
      for (int cc = 0; cc < 8; ++cc) {
        const int c = cg * 8 + cc;
        if (c < 125) {
          const float pre = fcpart[1][row][c];
          fcpart[0][row][c] = __fadd_rn(pre, p.fcb[125 * blk + c]);
        }
      }
      const int seg = cg;
      const float* sh = p.shat + (size_t)blk * 1024 + seg * 64;
      float s = 0.f;
#pragma unroll 8
      for (int i = 0; i < 64; ++i) {
        const float av = __builtin_fabsf((float)p.axh[4][faddr(seg * 64 + i, row)]) + 1e-5f;
        s += av * sh[i];
      }
      epart[row][seg] = s;
    }
    __syncthreads();
    {
      const int row = tid >> 4, cg = tid & 15;
      float m = -3.4e38f;
#pragma unroll
      for (int cc = 0; cc < 8; ++cc) {
        const int c = cg * 8 + cc;
        if (c < 125) m = fmaxf(m, fcpart[0][row][c]);
      }
      rmaxs[row][cg] = m;
    }
    __syncthreads();
    if (tid < 32) {
      float m = rmaxs[tid][0];
      float e = epart[tid][0];
#pragma unroll
      for (int s2 = 1; s2 < 16; ++s2) { m = fmaxf(m, rmaxs[tid][s2]); e += epart[tid][s2]; }
      rowmax[tid] = m;
      erow[tid] = 2.0f * (e * (1.0f / 2048.0f)) * 1.02f + 2e-5f;
    }
    __syncthreads();
    for (int idx = tid; idx < 32 * 128; idx += NTHR) {
      const int row = idx >> 7, c = idx & 127;
      if (c < 125) {
        if (fcpart[0][row][c] >= rowmax[row] - erow[row]) {
          const int pos = atomicAdd(&wcount, 1);
          wl[pos] = (row << 8) | c;
          atomicOr(&cand[row][c >> 5], 1u << (c & 31));
        }
      }
    }
    __syncthreads();
    if (w < 4) {
      const int row = tid >> 3, cg = tid & 7;
      float* orow = p.out + (size_t)row * (128 * 32000) + (size_t)t * 32000 + 125 * blk;
#pragma unroll
      for (int cc = 0; cc < 16; ++cc) {
        const int c = cg * 16 + cc;
        if (c < 125 && !((cand[row][c >> 5] >> (c & 31)) & 1u))
          __builtin_nontemporal_store(fcpart[0][row][c], orow + c);
      }
    } else {
      const int wcnt = wcount;
      for (int i = w - 4; i < wcnt; i += 4) {
        const int ent = wl[i];
        const int row = ent >> 8, cl = ent & 255;
        const int kb = lane * 16;
        const f16x8 A0h = *(const f16x8*)(p.axh[4] + faddr(kb, row));
        const f16x8 A0l = *(const f16x8*)(p.axl[4] + faddr(kb, row));
        const f16x8 A0m = *(const f16x8*)(p.axm[4] + faddr(kb, row));
        const f16x8 A1h = *(const f16x8*)(p.axh[4] + faddr(kb + 8, row));
        const f16x8 A1l = *(const f16x8*)(p.axl[4] + faddr(kb + 8, row));
        const f16x8 A1m = *(const f16x8*)(p.axm[4] + faddr(kb + 8, row));
        const f16* Lc = p.fcLc + (size_t)(125 * blk + cl) * 1024 + kb;
        const f16x8 L0 = *(const f16x8*)(Lc);
        const f16x8 L1 = *(const f16x8*)(Lc + 8);
        double d = 0.0;
#pragma unroll
        for (int e = 0; e < 8; ++e) {
          const double a0 = (double)A0h[e] + (double)A0l[e] * 0x1p-11 + (double)A0m[e] * 0x1p-22;
          const double a1 = (double)A1h[e] + (double)A1l[e] * 0x1p-11 + (double)A1m[e] * 0x1p-22;
          d += a0 * (double)L0[e] + a1 * (double)L1[e];
        }
#pragma unroll
        for (int m2 = 32; m2 >= 1; m2 >>= 1) d += __shfl_xor(d, m2, 64);
        if (lane == 0) {
          const float zr = __fadd_rn((float)((double)fcpart[1][row][cl] + d * 0x1p-11),
                                     p.fcb[125 * blk + cl]);
          atomicMax(&redu2[row], packvc(zr, (unsigned)(125 * blk + cl)));
          p.out[(size_t)row * (128 * 32000) + (size_t)t * 32000 + 125 * blk + cl] = zr;
        }
      }
    }
    __syncthreads();
    if (tid < 32) p.top[tid * 256 + blk] = redu2[tid];
    grid_bar5(p.bar, blk, ++genc);
  }

  // tail: token for t = 127
  if (blk < 32) {
    if (tid < 16) {
      const u64* tr = p.top + blk * 256 + tid * 16;
      u64 m = 0;
#pragma unroll
      for (int e = 0; e < 16; ++e) m = umax64(m, tr[e]);
      redu[0][tid] = m;
    }
    __syncthreads();
    if (tid == 0) {
      u64 mm = redu[0][0];
#pragma unroll
      for (int s2 = 1; s2 < 16; ++s2) mm = umax64(mm, redu[0][s2]);
      p.out[(size_t)32 * 128 * 32000 + (size_t)blk * 128 + 127] =
          (float)(0xFFFFFFFFu - (unsigned)(mm & 0xFFFFFFFFull));
    }
  }
}

// ---------------- host ----------------

extern "C" void kernel_launch(void* const* d_in, const int* in_sizes, int n_in,
                              void* d_out, int out_size, void* d_ws, size_t ws_size,
                              hipStream_t stream) {
  (void)in_sizes; (void)n_in; (void)out_size;
  const float* hini[4] = {(const float*)d_in[0], (const float*)d_in[2], (const float*)d_in[4], (const float*)d_in[6]};
  const float* cini[4] = {(const float*)d_in[1], (const float*)d_in[3], (const float*)d_in[5], (const float*)d_in[7]};
  const float* emb = (const float*)d_in[8];
  const float* Wx[4] = {(const float*)d_in[9], (const float*)d_in[12], (const float*)d_in[15], (const float*)d_in[18]};
  const float* Wh[4] = {(const float*)d_in[10], (const float*)d_in[13], (const float*)d_in[16], (const float*)d_in[19]};
  const float* bias[4] = {(const float*)d_in[11], (const float*)d_in[14], (const float*)d_in[17], (const float*)d_in[20]};
  const float* fcW = (const float*)d_in[21];
  const float* fcb = (const float*)d_in[22];

  char* ws = (char*)d_ws;
  size_t off = 0;
  auto take = [&](size_t bytes) -> char* {
    char* r = ws + off;
    off += (bytes + 255) & ~(size_t)255;
    return r;
  };
  f16* WfH[4]; f16* WfL[4];
  WfH[0] = (f16*)take((size_t)256 * 48 * 64 * 8 * 2);
  WfL[0] = (f16*)take((size_t)256 * 48 * 64 * 8 * 2);
  for (int l = 1; l < 4; ++l) {
    WfH[l] = (f16*)take((size_t)256 * 64 * 64 * 8 * 2);
    WfL[l] = (f16*)take((size_t)256 * 64 * 64 * 8 * 2);
  }
  f16* fcH = (f16*)take((size_t)256 * 8 * 32 * 64 * 8 * 2);
  f16* fcLc = (f16*)take((size_t)32000 * 1024 * 2);
  float* shat = (float*)take((size_t)256 * 1024 * 4);
  f16* axh[5]; f16* axl[5]; f16* axm[5];
  const int axK[5] = {1024, 2048, 2048, 2048, 1024};
  for (int l = 0; l < 5; ++l) {
    axh[l] = (f16*)take((size_t)axK[l] * 32 * 2);
    axl[l] = (f16*)take((size_t)axK[l] * 32 * 2);
    axm[l] = (f16*)take((size_t)axK[l] * 32 * 2);
  }
  u64* top = (u64*)take((size_t)32 * 256 * 8);
  unsigned* bar = (unsigned*)take(8192);

  if (off > ws_size) {
    hipLaunchKernelGGL(ws_sentinel, dim3(1), dim3(1), 0, stream, (float*)d_out);
    return;
  }

  hipMemsetAsync(bar, 0, 8192, stream);
  hipLaunchKernelGGL(prep_lstm, dim3(256 * 48 * 64 / 256), dim3(256), 0, stream,
                     Wx[0], Wh[0], 512, 48, WfH[0], WfL[0]);
  for (int l = 1; l < 4; ++l)
    hipLaunchKernelGGL(prep_lstm, dim3(256 * 64 * 64 / 256), dim3(256), 0, stream,
                       Wx[l], Wh[l], 1024, 64, WfH[l], WfL[l]);
  hipLaunchKernelGGL(prep_fc, dim3(256 * 8 * 32 * 64 / 256), dim3(256), 0, stream,
                     fcW, fcH);
  hipLaunchKernelGGL(prep_fclT, dim3(500), dim3(256), 0, stream, fcW, fcLc);
  hipLaunchKernelGGL(prep_shat, dim3(1024), dim3(256), 0, stream, fcW, shat);

  MainP mp;
  mp.emb = emb;
  for (int l = 0; l < 4; ++l) {
    mp.bias[l] = bias[l]; mp.hini[l] = hini[l]; mp.cini[l] = cini[l];
    mp.WfH[l] = WfH[l]; mp.WfL[l] = WfL[l];
  }
  mp.fcb = fcb; mp.fcH = fcH; mp.fcLc = fcLc; mp.shat = shat;
  for (int l = 0; l < 5; ++l) { mp.axh[l] = axh[l]; mp.axl[l] = axl[l]; mp.axm[l] = axm[l]; }
  mp.top = top; mp.bar = bar; mp.out = (float*)d_out;

  void* args[] = {&mp};
  hipLaunchCooperativeKernel((void*)lstm_main, dim3(NBLK), dim3(NTHR), args, 0, stream);
}